// Round 1
// baseline (144.304 us; speedup 1.0000x reference)
//
#include <hip/hip_runtime.h>
#include <hip/hip_bf16.h>

// Problem shapes (fixed by reference setup_inputs):
//   b=512, N=50, p=32, T=AT=4000, NN=2500
// Inputs: x[512,50,32] f32, x_i[512,32] i32, y_i[512] i32, g[2500,2500] f32,
//         weights[2500] f32, mus[4000,50] f32, alphas[4000] f32
// Output: Z[512,50] then F[2500]  (28100 f32)

#define NB   512
#define NN   50
#define NP   32
#define NT   4000
#define NNN  2500   // N*N

// ---------------- Kernel 1: F[k] = sum_m g[k,m] * w[m]^2 ----------------
__global__ void __launch_bounds__(256) k_F(const float* __restrict__ g,
                                           const float* __restrict__ w,
                                           float* __restrict__ F) {
    const int k = blockIdx.x;
    const float* row = g + (size_t)k * NNN;
    float s = 0.f;
    for (int m = threadIdx.x; m < NNN; m += 256) {
        float wm = w[m];
        s += row[m] * (wm * wm);
    }
    // wave64 reduce
    #pragma unroll
    for (int off = 32; off; off >>= 1) s += __shfl_down(s, off, 64);
    __shared__ float part[4];
    const int wave = threadIdx.x >> 6;
    const int lane = threadIdx.x & 63;
    if (lane == 0) part[wave] = s;
    __syncthreads();
    if (threadIdx.x == 0) F[k] = part[0] + part[1] + part[2] + part[3];
}

// ------- Kernel 2: f[t,i,j] = softmax_j( -alphas[t] * F[i*50+j] ) --------
__global__ void __launch_bounds__(256) k_soft(const float* __restrict__ F,
                                              const float* __restrict__ alphas,
                                              float* __restrict__ f) {
    const int t = blockIdx.x;
    const float alpha = alphas[t];
    const int wave = threadIdx.x >> 6;
    const int lane = threadIdx.x & 63;

    __shared__ float Fs[NNN];
    for (int m = threadIdx.x; m < NNN; m += 256) Fs[m] = F[m];
    __syncthreads();

    float* out = f + (size_t)t * NNN;
    for (int i = wave; i < NN; i += 4) {
        float v = (lane < NN) ? (-alpha * Fs[i * NN + lane]) : -1e30f;
        float mx = v;
        #pragma unroll
        for (int off = 32; off; off >>= 1) mx = fmaxf(mx, __shfl_xor(mx, off, 64));
        float e = (lane < NN) ? __expf(v - mx) : 0.f;
        float sum = e;
        #pragma unroll
        for (int off = 32; off; off >>= 1) sum += __shfl_xor(sum, off, 64);
        if (lane < NN) out[i * NN + lane] = e / sum;
    }
}

// ------------- Kernel 3: gathered einsum + reduction over p --------------
// Z[bb,i] = sum_pp sum_j f[x_i[bb,pp], i, j] * (x[bb,j,pp] - mus[x_i[bb,pp], j])
//           + 32 * mus[y_i[bb], i]
__global__ void __launch_bounds__(256) k_Z(const float* __restrict__ x,
                                           const int* __restrict__ x_i,
                                           const int* __restrict__ y_i,
                                           const float* __restrict__ mus,
                                           const float* __restrict__ f,
                                           float* __restrict__ Z) {
    const int bb = blockIdx.x;

    __shared__ float a[NP][NN + 2];   // a[pp][j]
    __shared__ int   ti[NP];
    __shared__ float zsh[64];

    if (threadIdx.x < NP) ti[threadIdx.x] = x_i[bb * NP + threadIdx.x];
    if (threadIdx.x < 64) zsh[threadIdx.x] = 0.f;
    __syncthreads();

    // a[pp][j] = x[bb, j, pp] - mus[ti[pp], j]   (x read coalesced)
    for (int idx = threadIdx.x; idx < NN * NP; idx += 256) {
        const int j  = idx >> 5;
        const int pp = idx & 31;
        a[pp][j] = x[(size_t)bb * (NN * NP) + idx] - mus[(size_t)ti[pp] * NN + j];
    }
    __syncthreads();

    // 1600 (pp,i) pairs; each is a length-50 dot of f-row (global, L2/L3) with a (LDS)
    for (int q = threadIdx.x; q < NP * NN; q += 256) {
        const int pp = q / NN;
        const int i  = q - pp * NN;
        const float* __restrict__ frow = f + (size_t)ti[pp] * NNN + i * NN;
        const float* __restrict__ arow = a[pp];
        float s = 0.f;
        #pragma unroll
        for (int j = 0; j < NN; ++j) s += frow[j] * arow[j];
        atomicAdd(&zsh[i], s);
    }
    __syncthreads();

    if (threadIdx.x < NN) {
        Z[bb * NN + threadIdx.x] =
            zsh[threadIdx.x] + 32.f * mus[(size_t)y_i[bb] * NN + threadIdx.x];
    }
}

extern "C" void kernel_launch(void* const* d_in, const int* in_sizes, int n_in,
                              void* d_out, int out_size, void* d_ws, size_t ws_size,
                              hipStream_t stream) {
    const float* x      = (const float*)d_in[0];
    const int*   x_i    = (const int*)  d_in[1];
    const int*   y_i    = (const int*)  d_in[2];
    const float* g      = (const float*)d_in[3];
    const float* w      = (const float*)d_in[4];
    const float* mus    = (const float*)d_in[5];
    const float* alphas = (const float*)d_in[6];

    float* Z = (float*)d_out;              // [512*50]
    float* F = Z + NB * NN;                // [2500]
    float* f = (float*)d_ws;               // [4000*2500] = 40 MB scratch

    k_F   <<<NNN, 256, 0, stream>>>(g, w, F);
    k_soft<<<NT,  256, 0, stream>>>(F, alphas, f);
    k_Z   <<<NB,  256, 0, stream>>>(x, x_i, y_i, mus, f, Z);
}

// Round 2
// 105.480 us; speedup vs baseline: 1.3681x; 1.3681x over previous
//
#include <hip/hip_runtime.h>
#include <hip/hip_bf16.h>

// Shapes fixed by reference setup_inputs():
//   b=512, N=50, p=32, T=AT=4000, NN=2500
// Inputs: x[512,50,32] f32, x_i[512,32] i32, y_i[512] i32, g[2500,2500] f32,
//         weights[2500] f32, mus[4000,50] f32, alphas[4000] f32
// Output: Z[512,50] then F[2500]  (28100 f32)
//
// Key identity: f[t,i,j] = softmax_j(-alpha_t * F[i,j]); alpha_t > 0 so the
// row max is -alpha_t * min_j F[i,j]. Softmax is recomputed on the fly from
// the 10 KB F tile in LDS -- f (40 MB) is never materialized.

#define NB   512
#define NN   50
#define NP   32
#define NNN  2500   // N*N

// ---------------- Kernel 1: F[k] = sum_m g[k,m] * w[m]^2 ----------------
__global__ void __launch_bounds__(256) k_F(const float* __restrict__ g,
                                           const float* __restrict__ w,
                                           float* __restrict__ F) {
    const int k = blockIdx.x;
    const float4* __restrict__ row4 = (const float4*)(g + (size_t)k * NNN);
    const float4* __restrict__ w4   = (const float4*)w;
    float s = 0.f;
    for (int m = threadIdx.x; m < NNN / 4; m += 256) {   // 625 float4 per row
        float4 gv = row4[m];
        float4 wv = w4[m];
        s += gv.x * (wv.x * wv.x) + gv.y * (wv.y * wv.y)
           + gv.z * (wv.z * wv.z) + gv.w * (wv.w * wv.w);
    }
    #pragma unroll
    for (int off = 32; off; off >>= 1) s += __shfl_down(s, off, 64);
    __shared__ float part[4];
    if ((threadIdx.x & 63) == 0) part[threadIdx.x >> 6] = s;
    __syncthreads();
    if (threadIdx.x == 0) F[k] = part[0] + part[1] + part[2] + part[3];
}

// ---- Kernel 2 (fused): on-the-fly softmax + gathered einsum + p-reduce ----
// Z[bb,i] = sum_pp sum_j softmax_j(-a_t F[i,:])[j] * (x[bb,j,pp]-mus[t,j])
//           + 32 * mus[y_i[bb], i],   t = x_i[bb,pp]
__global__ void __launch_bounds__(256) k_Z(const float* __restrict__ x,
                                           const int* __restrict__ x_i,
                                           const int* __restrict__ y_i,
                                           const float* __restrict__ mus,
                                           const float* __restrict__ alphas,
                                           const float* __restrict__ F,
                                           float* __restrict__ Z) {
    const int bb  = blockIdx.x;
    const int tid = threadIdx.x;

    __shared__ float Fs[NN][NN + 1];   // padded: stride 51 -> <=2-way banks (free)
    __shared__ float Fmin[NN];
    __shared__ float a[NP][NN + 1];
    __shared__ float alph[NP];
    __shared__ int   ti[NP];
    __shared__ float zsh[NN];

    // stage F (padded), indices, alphas; zero z accumulator
    for (int idx = tid; idx < NNN; idx += 256) {
        Fs[idx / NN][idx % NN] = F[idx];
    }
    if (tid < NP) {
        int t = x_i[bb * NP + tid];
        ti[tid]   = t;
        alph[tid] = alphas[t];
    }
    if (tid < NN) zsh[tid] = 0.f;
    __syncthreads();

    // Fmin[i] = min_j F[i,j]
    if (tid < NN) {
        float m = Fs[tid][0];
        #pragma unroll
        for (int j = 1; j < NN; ++j) m = fminf(m, Fs[tid][j]);
        Fmin[tid] = m;
    }
    // a[pp][j] = x[bb, j, pp] - mus[ti[pp], j]   (x read coalesced)
    for (int idx = tid; idx < NN * NP; idx += 256) {
        const int j  = idx >> 5;
        const int pp = idx & 31;
        a[pp][j] = x[(size_t)bb * (NN * NP) + idx] - mus[(size_t)ti[pp] * NN + j];
    }
    __syncthreads();

    // 1600 (pp,i) pairs: z[i] += sum_j exp(alpha*(Fmin_i - F[i,j])) * a[pp][j] / den
    for (int q = tid; q < NP * NN; q += 256) {
        const int pp = q / NN;
        const int i  = q - pp * NN;
        const float  alpha = alph[pp];
        const float  fmn   = Fmin[i];
        const float* __restrict__ frow = Fs[i];
        const float* __restrict__ arow = a[pp];
        float num = 0.f, den = 0.f;
        #pragma unroll
        for (int j = 0; j < NN; ++j) {
            float e = __expf(alpha * (fmn - frow[j]));
            num += e * arow[j];
            den += e;
        }
        atomicAdd(&zsh[i], num / den);
    }
    __syncthreads();

    if (tid < NN) {
        Z[bb * NN + tid] = zsh[tid] + 32.f * mus[(size_t)y_i[bb] * NN + tid];
    }
}

extern "C" void kernel_launch(void* const* d_in, const int* in_sizes, int n_in,
                              void* d_out, int out_size, void* d_ws, size_t ws_size,
                              hipStream_t stream) {
    const float* x      = (const float*)d_in[0];
    const int*   x_i    = (const int*)  d_in[1];
    const int*   y_i    = (const int*)  d_in[2];
    const float* g      = (const float*)d_in[3];
    const float* w      = (const float*)d_in[4];
    const float* mus    = (const float*)d_in[5];
    const float* alphas = (const float*)d_in[6];

    float* Z = (float*)d_out;              // [512*50]
    float* F = Z + NB * NN;                // [2500] (second output)

    k_F<<<NNN, 256, 0, stream>>>(g, w, F);
    k_Z<<<NB,  256, 0, stream>>>(x, x_i, y_i, mus, alphas, F, Z);
}

// Round 3
// 99.471 us; speedup vs baseline: 1.4507x; 1.0604x over previous
//
#include <hip/hip_runtime.h>
#include <hip/hip_bf16.h>

// Shapes fixed by reference setup_inputs():
//   b=512, N=50, p=32, T=AT=4000, NN=2500
// Output: Z[512,50] then F[2500]  (28100 f32)
//
// f[t,i,j] = softmax_j(-alpha_t * F[i,j]) is recomputed on the fly (alpha>0
// so row-max = -alpha*min_j F). Each lane owns one output row i: its
// d[j] = Fmin_i - F[i,j] lives in 52 registers; a[pp][:] comes in as
// wave-uniform ds_read_b128 broadcasts. No f materialization, no LDS atomics.

#define NB   512
#define NN   50
#define NP   32
#define NNN  2500
#define FSTR 52     // row stride (floats): 52*4 B = 13*16 B, odd multiple of 16 B

// ---------------- Kernel 1: F[k] = sum_m g[k,m] * w[m]^2 ----------------
__global__ void __launch_bounds__(256) k_F(const float* __restrict__ g,
                                           const float* __restrict__ w,
                                           float* __restrict__ F) {
    const int k = blockIdx.x;
    const float4* __restrict__ row4 = (const float4*)(g + (size_t)k * NNN);
    const float4* __restrict__ w4   = (const float4*)w;
    float s = 0.f;
    for (int m = threadIdx.x; m < NNN / 4; m += 256) {   // 625 float4 per row
        float4 gv = row4[m];
        float4 wv = w4[m];
        s += gv.x * (wv.x * wv.x) + gv.y * (wv.y * wv.y)
           + gv.z * (wv.z * wv.z) + gv.w * (wv.w * wv.w);
    }
    #pragma unroll
    for (int off = 32; off; off >>= 1) s += __shfl_down(s, off, 64);
    __shared__ float part[4];
    if ((threadIdx.x & 63) == 0) part[threadIdx.x >> 6] = s;
    __syncthreads();
    if (threadIdx.x == 0) F[k] = part[0] + part[1] + part[2] + part[3];
}

// ---- Kernel 2 (fused): on-the-fly softmax + gathered einsum + p-reduce ----
__global__ void __launch_bounds__(512) k_Z(const float* __restrict__ x,
                                           const int* __restrict__ x_i,
                                           const int* __restrict__ y_i,
                                           const float* __restrict__ mus,
                                           const float* __restrict__ alphas,
                                           const float* __restrict__ F,
                                           float* __restrict__ Z) {
    const int bb   = blockIdx.x;
    const int tid  = threadIdx.x;
    const int wave = tid >> 6;           // 0..7, handles pp = wave*4 + s
    const int lane = tid & 63;           // lane<50 owns output row i=lane

    __shared__ float Fs[NN * FSTR];      // cols 50,51 padded with +inf
    __shared__ float a[NP][FSTR];        // cols 50,51 padded with 0
    __shared__ float alph[NP];
    __shared__ float zp[8][NN];

    // ---- stage: Fs (padded), a[pp][j] = x[bb,j,pp] - mus[t_pp,j], alphas ----
    for (int idx = tid; idx < NN * FSTR; idx += 512) {
        const int r = idx / FSTR, c = idx - r * FSTR;
        Fs[idx] = (c < NN) ? F[r * NN + c] : __builtin_huge_valf();
    }
    if (tid < NP) {
        const int t = x_i[bb * NP + tid];
        alph[tid] = alphas[t];
        a[tid][NN] = 0.f; a[tid][NN + 1] = 0.f;
    }
    for (int idx = tid; idx < NN * NP; idx += 512) {     // coalesced x read
        const int j  = idx >> 5;
        const int pp = idx & 31;
        const int t  = x_i[bb * NP + pp];                // L1-cached re-read
        a[pp][j] = x[(size_t)bb * (NN * NP) + idx] - mus[(size_t)t * NN + j];
    }
    __syncthreads();

    // ---- per-lane row into registers: d[j] = Fmin - F[i,j] (pads -> -inf) ----
    const int row = (lane < NN) ? lane : 0;
    const float4* __restrict__ frow4 = (const float4*)(Fs + row * FSTR);
    float4 rv[13];
    #pragma unroll
    for (int k = 0; k < 13; ++k) rv[k] = frow4[k];
    float mn = rv[0].x;
    #pragma unroll
    for (int k = 0; k < 13; ++k)
        mn = fminf(mn, fminf(fminf(rv[k].x, rv[k].y), fminf(rv[k].z, rv[k].w)));
    float d[FSTR];
    #pragma unroll
    for (int k = 0; k < 13; ++k) {
        d[4 * k + 0] = mn - rv[k].x;
        d[4 * k + 1] = mn - rv[k].y;
        d[4 * k + 2] = mn - rv[k].z;
        d[4 * k + 3] = mn - rv[k].w;     // pads: mn - inf = -inf -> exp = 0
    }

    // ---- main: 4 pp per wave; a-row via wave-uniform b128 broadcast ----
    float zacc = 0.f;
    #pragma unroll 1
    for (int s = 0; s < 4; ++s) {
        const int pp = (wave << 2) + s;
        const float al = alph[pp];
        const float4* __restrict__ arow4 = (const float4*)(a[pp]);
        float num = 0.f, den = 0.f;
        #pragma unroll
        for (int k = 0; k < 13; ++k) {
            const float4 av = arow4[k];
            float e0 = __expf(al * d[4 * k + 0]); den += e0; num = fmaf(e0, av.x, num);
            float e1 = __expf(al * d[4 * k + 1]); den += e1; num = fmaf(e1, av.y, num);
            float e2 = __expf(al * d[4 * k + 2]); den += e2; num = fmaf(e2, av.z, num);
            float e3 = __expf(al * d[4 * k + 3]); den += e3; num = fmaf(e3, av.w, num);
        }
        zacc += num / den;               // den >= 1 (row contains its min)
    }
    if (lane < NN) zp[wave][lane] = zacc;
    __syncthreads();

    if (tid < NN) {
        float z = zp[0][tid] + zp[1][tid] + zp[2][tid] + zp[3][tid]
                + zp[4][tid] + zp[5][tid] + zp[6][tid] + zp[7][tid];
        Z[bb * NN + tid] = z + 32.f * mus[(size_t)y_i[bb] * NN + tid];
    }
}

extern "C" void kernel_launch(void* const* d_in, const int* in_sizes, int n_in,
                              void* d_out, int out_size, void* d_ws, size_t ws_size,
                              hipStream_t stream) {
    const float* x      = (const float*)d_in[0];
    const int*   x_i    = (const int*)  d_in[1];
    const int*   y_i    = (const int*)  d_in[2];
    const float* g      = (const float*)d_in[3];
    const float* w      = (const float*)d_in[4];
    const float* mus    = (const float*)d_in[5];
    const float* alphas = (const float*)d_in[6];

    float* Z = (float*)d_out;              // [512*50]
    float* F = Z + NB * NN;                // [2500] (second output)

    k_F<<<NNN, 256, 0, stream>>>(g, w, F);
    k_Z<<<NB,  512, 0, stream>>>(x, x_i, y_i, mus, alphas, F, Z);
}

// Round 4
// 98.411 us; speedup vs baseline: 1.4663x; 1.0108x over previous
//
#include <hip/hip_runtime.h>
#include <hip/hip_bf16.h>

// Shapes fixed by reference setup_inputs():
//   b=512, N=50, p=32, T=AT=4000, NN=2500
// Output: Z[512,50] then F[2500]  (28100 f32)
//
// f[t,i,j] = softmax_j(-alpha_t * F[i,j]) recomputed on the fly (alpha>0 so
// row-max = -alpha*min_j F). Lane owns row i: d[j]=Fmin-F[i,j] in registers;
// a[pp][:] arrives as wave-uniform ds_read_b128 broadcasts. No f tensor, no
// LDS atomics. Inner loop trimmed to exactly 50 elems; fast rcp for /den.

#define NB   512
#define NN   50
#define NP   32
#define NNN  2500
#define FSTR 52     // LDS row stride (floats): 13*16 B, odd multiple of 16 B

// ---------------- Kernel 1: F[k] = sum_m g[k,m] * w[m]^2 ----------------
__global__ void __launch_bounds__(256) k_F(const float* __restrict__ g,
                                           const float* __restrict__ w,
                                           float* __restrict__ F) {
    const int k = blockIdx.x;
    const float4* __restrict__ row4 = (const float4*)(g + (size_t)k * NNN);
    const float4* __restrict__ w4   = (const float4*)w;
    float s = 0.f;
    for (int m = threadIdx.x; m < NNN / 4; m += 256) {   // 625 float4 per row
        float4 gv = row4[m];
        float4 wv = w4[m];
        s += gv.x * (wv.x * wv.x) + gv.y * (wv.y * wv.y)
           + gv.z * (wv.z * wv.z) + gv.w * (wv.w * wv.w);
    }
    #pragma unroll
    for (int off = 32; off; off >>= 1) s += __shfl_down(s, off, 64);
    __shared__ float part[4];
    if ((threadIdx.x & 63) == 0) part[threadIdx.x >> 6] = s;
    __syncthreads();
    if (threadIdx.x == 0) F[k] = part[0] + part[1] + part[2] + part[3];
}

// ---- Kernel 2 (fused): on-the-fly softmax + gathered einsum + p-reduce ----
__global__ void __launch_bounds__(512) k_Z(const float* __restrict__ x,
                                           const int* __restrict__ x_i,
                                           const int* __restrict__ y_i,
                                           const float* __restrict__ mus,
                                           const float* __restrict__ alphas,
                                           const float* __restrict__ F,
                                           float* __restrict__ Z) {
    const int bb   = blockIdx.x;
    const int tid  = threadIdx.x;
    const int wave = tid >> 6;           // 0..7, handles pp = wave*4 + s
    const int lane = tid & 63;           // lane<50 owns output row i=lane

    __shared__ float Fs[NN * FSTR];
    __shared__ float a[NP][FSTR];
    __shared__ float alph[NP];
    __shared__ float zp[8][NN];

    // ---- stage: Fs, a[pp][j] = x[bb,j,pp] - mus[t_pp,j], alphas ----
    for (int idx = tid; idx < NN * FSTR; idx += 512) {
        const int r = idx / FSTR, c = idx - r * FSTR;
        Fs[idx] = (c < NN) ? F[r * NN + c] : 0.f;        // pads unread
    }
    if (tid < NP) {
        const int t = x_i[bb * NP + tid];
        alph[tid] = alphas[t];
    }
    for (int idx = tid; idx < NN * NP; idx += 512) {     // coalesced x read
        const int j  = idx >> 5;
        const int pp = idx & 31;
        const int t  = x_i[bb * NP + pp];                // L1-cached re-read
        a[pp][j] = x[(size_t)bb * (NN * NP) + idx] - mus[(size_t)t * NN + j];
    }
    __syncthreads();

    // ---- per-lane row into registers: d[j] = Fmin - F[i,j], 50 exact ----
    const int row = (lane < NN) ? lane : 0;
    const float4* __restrict__ frow4 = (const float4*)(Fs + row * FSTR);
    float4 rv[12];
    #pragma unroll
    for (int k = 0; k < 12; ++k) rv[k] = frow4[k];
    const float2 rt = ((const float2*)frow4)[24];        // elems 48,49
    float mn = fminf(rt.x, rt.y);
    #pragma unroll
    for (int k = 0; k < 12; ++k)
        mn = fminf(mn, fminf(fminf(rv[k].x, rv[k].y), fminf(rv[k].z, rv[k].w)));
    float d[NN];
    #pragma unroll
    for (int k = 0; k < 12; ++k) {
        d[4 * k + 0] = mn - rv[k].x;
        d[4 * k + 1] = mn - rv[k].y;
        d[4 * k + 2] = mn - rv[k].z;
        d[4 * k + 3] = mn - rv[k].w;
    }
    d[48] = mn - rt.x;
    d[49] = mn - rt.y;

    // ---- main: 4 pp per wave; a-row via wave-uniform b128 broadcast ----
    float zacc = 0.f;
    #pragma unroll 1
    for (int s = 0; s < 4; ++s) {
        const int pp = (wave << 2) + s;
        const float al = alph[pp];
        const float4* __restrict__ arow4 = (const float4*)(a[pp]);
        float num = 0.f, den = 0.f;
        #pragma unroll
        for (int k = 0; k < 12; ++k) {
            const float4 av = arow4[k];
            float e0 = __expf(al * d[4 * k + 0]); den += e0; num = fmaf(e0, av.x, num);
            float e1 = __expf(al * d[4 * k + 1]); den += e1; num = fmaf(e1, av.y, num);
            float e2 = __expf(al * d[4 * k + 2]); den += e2; num = fmaf(e2, av.z, num);
            float e3 = __expf(al * d[4 * k + 3]); den += e3; num = fmaf(e3, av.w, num);
        }
        const float2 at = ((const float2*)arow4)[24];
        float e48 = __expf(al * d[48]); den += e48; num = fmaf(e48, at.x, num);
        float e49 = __expf(al * d[49]); den += e49; num = fmaf(e49, at.y, num);
        zacc = fmaf(num, __builtin_amdgcn_rcpf(den), zacc);   // den >= 1
    }
    if (lane < NN) zp[wave][lane] = zacc;
    __syncthreads();

    if (tid < NN) {
        float z = zp[0][tid] + zp[1][tid] + zp[2][tid] + zp[3][tid]
                + zp[4][tid] + zp[5][tid] + zp[6][tid] + zp[7][tid];
        Z[bb * NN + tid] = z + 32.f * mus[(size_t)y_i[bb] * NN + tid];
    }
}

extern "C" void kernel_launch(void* const* d_in, const int* in_sizes, int n_in,
                              void* d_out, int out_size, void* d_ws, size_t ws_size,
                              hipStream_t stream) {
    const float* x      = (const float*)d_in[0];
    const int*   x_i    = (const int*)  d_in[1];
    const int*   y_i    = (const int*)  d_in[2];
    const float* g      = (const float*)d_in[3];
    const float* w      = (const float*)d_in[4];
    const float* mus    = (const float*)d_in[5];
    const float* alphas = (const float*)d_in[6];

    float* Z = (float*)d_out;              // [512*50]
    float* F = Z + NB * NN;                // [2500] (second output)

    k_F<<<NNN, 256, 0, stream>>>(g, w, F);
    k_Z<<<NB,  512, 0, stream>>>(x, x_i, y_i, mus, alphas, F, Z);
}